// Round 1
// baseline (741.169 us; speedup 1.0000x reference)
//
#include <hip/hip_runtime.h>
#include <cstdint>
#include <cstddef>

typedef __attribute__((ext_vector_type(4))) float f32x4;
typedef __attribute__((ext_vector_type(8))) short s16x8;

#define DEVINL __device__ __forceinline__

DEVINL unsigned short f2bf(float f){
  union { float f; unsigned u; } v; v.f = f;
  unsigned r = v.u + 0x7fffu + ((v.u >> 16) & 1u);  // RNE
  return (unsigned short)(r >> 16);
}
DEVINL float bf2f(unsigned short h){
  union { unsigned u; float f; } v; v.u = ((unsigned)h) << 16;
  return v.f;
}
DEVINL void gload_lds16(const void* g, void* l){
  __builtin_amdgcn_global_load_lds((const __attribute__((address_space(1))) void*)g,
                                   (__attribute__((address_space(3))) void*)l, 16, 0, 0);
}

// ---- weight prep: Wt[n][k] = bf16(W[k][n] * (C ? C[k][n] : 1)), zero for n>=N ----
__global__ __launch_bounds__(256) void transpose_bf16(
    const float* __restrict__ W, const float* __restrict__ C,
    unsigned short* __restrict__ Wt, int K, int N, int Npad)
{
  __shared__ unsigned short tile[32][33];
  int k0 = blockIdx.x * 32, n0 = blockIdx.y * 32;
  int tx = threadIdx.x & 31, ty = threadIdx.x >> 5;
  #pragma unroll
  for (int i = 0; i < 4; ++i) {
    int k = k0 + ty + 8*i, n = n0 + tx;
    float v = 0.f;
    if (k < K && n < N) {
      v = W[(size_t)k*N + n];
      if (C) v *= C[(size_t)k*N + n];
    }
    tile[ty + 8*i][tx] = f2bf(v);
  }
  __syncthreads();
  #pragma unroll
  for (int i = 0; i < 4; ++i) {
    int n = n0 + ty + 8*i, k = k0 + tx;
    if (n < Npad && k < K) Wt[(size_t)n*K + k] = tile[tx][ty + 8*i];
  }
}

// ---- MFMA GEMM: C = act(A[M,K] * Bt[N,K]^T + bias) ----
// A fp32 (convert in staging) or bf16 (global_load_lds); Bt bf16 via global_load_lds.
// ACT: 0 = relu, 1 = sigmoid. Grid: (M/BM, N/BN), 256 threads (4 waves, 2x2).
template<int BM, int BN, bool A_FP32, int ACT, bool OUT_BF16>
__global__ __launch_bounds__(256) void gemm_mfma(
    const void* __restrict__ Aptr, const unsigned short* __restrict__ Bt,
    const float* __restrict__ bias, int biasN,
    void* __restrict__ Cptr, int K, int ldC)
{
  constexpr int BK = 32;
  constexpr int HM = BM/2, HN = BN/2;
  constexpr int FM = HM/16, FN = HN/16;
  __shared__ __align__(16) unsigned short As[BM*BK];
  __shared__ __align__(16) unsigned short Bs[BN*BK];
  const int tid  = threadIdx.x;
  const int lane = tid & 63;
  const int w    = tid >> 6;
  const int wm = w & 1, wn = w >> 1;
  const int q = lane >> 4, l16 = lane & 15;
  const long m0 = (long)blockIdx.x * BM;
  const long n0 = (long)blockIdx.y * BN;

  f32x4 acc[FM][FN] = {};

  for (int k0 = 0; k0 < K; k0 += BK) {
    if constexpr (A_FP32) {
      const float* Af = (const float*)Aptr;
      #pragma unroll
      for (int it = 0; it < BM/32; ++it) {
        int seg = tid + it*256;          // 4 floats per segment, 8 segs/row
        int row = seg >> 3;
        int c4  = (seg & 7) * 4;
        float4 v = *(const float4*)(Af + (m0 + row) * (long)K + k0 + c4);
        uint2 p;
        p.x = (unsigned)f2bf(v.x) | ((unsigned)f2bf(v.y) << 16);
        p.y = (unsigned)f2bf(v.z) | ((unsigned)f2bf(v.w) << 16);
        *(uint2*)&As[row*BK + c4] = p;
      }
    } else {
      const unsigned short* Ab = (const unsigned short*)Aptr;
      #pragma unroll
      for (int it = 0; it < BM/64; ++it) {
        int seg = tid + it*256;          // 8 bf16 (16B) per segment, 4 segs/row
        int row = seg >> 2;
        gload_lds16(Ab + (m0 + row) * (long)K + k0 + (seg & 3) * 8,
                    (char*)As + seg*16);
      }
    }
    #pragma unroll
    for (int it = 0; it < BN/64; ++it) {
      int seg = tid + it*256;
      int row = seg >> 2;
      gload_lds16(Bt + (n0 + row) * (long)K + k0 + (seg & 3) * 8,
                  (char*)Bs + seg*16);
    }
    __syncthreads();

    s16x8 a[FM], b[FN];
    #pragma unroll
    for (int i = 0; i < FM; ++i)
      a[i] = *(const s16x8*)&As[(wm*HM + i*16 + l16)*BK + q*8];
    #pragma unroll
    for (int j = 0; j < FN; ++j)
      b[j] = *(const s16x8*)&Bs[(wn*HN + j*16 + l16)*BK + q*8];
    #pragma unroll
    for (int i = 0; i < FM; ++i)
      #pragma unroll
      for (int j = 0; j < FN; ++j)
        acc[i][j] = __builtin_amdgcn_mfma_f32_16x16x32_bf16(a[i], b[j], acc[i][j], 0, 0, 0);
    __syncthreads();
  }

  // epilogue: D col = lane&15, row = (lane>>4)*4 + r   [m89/m91-verified layout]
  #pragma unroll
  for (int j = 0; j < FN; ++j) {
    long col = n0 + wn*HN + j*16 + l16;
    float bv = (col < biasN) ? bias[col] : 0.f;
    #pragma unroll
    for (int i = 0; i < FM; ++i) {
      #pragma unroll
      for (int r = 0; r < 4; ++r) {
        long row = m0 + wm*HM + i*16 + q*4 + r;
        float v = acc[i][j][r] + bv;
        if (ACT == 0) v = fmaxf(v, 0.f);
        else          v = 1.f / (1.f + __expf(-v));
        if (OUT_BF16) ((unsigned short*)Cptr)[row*(long)ldC + col] = f2bf(v);
        else          ((float*)Cptr)[row*(long)ldC + col] = v;
      }
    }
  }
}

// ---- L2: h2 = relu(h1[M,196(pad256)] @ (W2*C2)[196,10] + b2), one wave per row ----
__global__ __launch_bounds__(64) void layer2_kernel(
    const unsigned short* __restrict__ h1, const float* __restrict__ W2,
    const float* __restrict__ C2, const float* __restrict__ b2,
    float* __restrict__ h2)
{
  const int m = blockIdx.x;
  const int t = threadIdx.x;
  float acc[10];
  #pragma unroll
  for (int n = 0; n < 10; ++n) acc[n] = 0.f;
  for (int k = t; k < 196; k += 64) {
    float a = bf2f(h1[(size_t)m*256 + k]);
    #pragma unroll
    for (int n = 0; n < 10; ++n) acc[n] += a * W2[k*10 + n] * C2[k*10 + n];
  }
  #pragma unroll
  for (int off = 32; off > 0; off >>= 1) {
    #pragma unroll
    for (int n = 0; n < 10; ++n) acc[n] += __shfl_down(acc[n], off, 64);
  }
  if (t == 0) {
    #pragma unroll
    for (int n = 0; n < 10; ++n) h2[(size_t)m*10 + n] = fmaxf(acc[n] + b2[n], 0.f);
  }
}

// ---- L3: h3 = relu(h2[M,10] @ W3[10,1024] + b3) -> bf16 ----
__global__ __launch_bounds__(256) void layer3_kernel(
    const float* __restrict__ h2, const float* __restrict__ W3,
    const float* __restrict__ b3, unsigned short* __restrict__ h3)
{
  const int m = blockIdx.x;
  const int n = blockIdx.y * 256 + threadIdx.x;
  __shared__ float hs[10];
  if (threadIdx.x < 10) hs[threadIdx.x] = h2[(size_t)m*10 + threadIdx.x];
  __syncthreads();
  float acc = b3[n];
  #pragma unroll
  for (int k = 0; k < 10; ++k) acc += hs[k] * W3[k*1024 + n];
  h3[(size_t)m*1024 + n] = f2bf(fmaxf(acc, 0.f));
}

// ---- L4: z = relu(h3[M,1024] @ W4[1024,32] + b4) -> bf16; 8 rows/block ----
__global__ __launch_bounds__(256) void layer4_kernel(
    const unsigned short* __restrict__ h3, const float* __restrict__ W4,
    const float* __restrict__ b4, unsigned short* __restrict__ z)
{
  __shared__ __align__(16) unsigned short hs[8*1024];
  const int t = threadIdx.x;
  const long mb = (long)blockIdx.x * 8;
  const uint4* src = (const uint4*)(h3 + mb*1024);
  #pragma unroll
  for (int i = 0; i < 4; ++i) ((uint4*)hs)[t + i*256] = src[t + i*256];
  __syncthreads();
  const int n = t & 31, ml = t >> 5;
  const unsigned short* hr = hs + ml*1024;
  float acc = b4[n];
  for (int k8 = 0; k8 < 1024; k8 += 8) {
    uint4 hv = *(const uint4*)(hr + k8);
    const unsigned short* hu = (const unsigned short*)&hv;
    #pragma unroll
    for (int j = 0; j < 8; ++j) acc += bf2f(hu[j]) * W4[(k8 + j)*32 + n];
  }
  z[(mb + ml)*32 + n] = f2bf(fmaxf(acc, 0.f));
}

// ---- L5: d1 = relu(z[M,32] @ Wd1[32,1024] + bd1) -> bf16 ----
__global__ __launch_bounds__(256) void layer5_kernel(
    const unsigned short* __restrict__ z, const float* __restrict__ Wd1,
    const float* __restrict__ bd1, unsigned short* __restrict__ d1)
{
  const int m = blockIdx.x;
  const int n = blockIdx.y * 256 + threadIdx.x;
  __shared__ float zs[32];
  if (threadIdx.x < 32) zs[threadIdx.x] = bf2f(z[(size_t)m*32 + threadIdx.x]);
  __syncthreads();
  float acc = bd1[n];
  #pragma unroll
  for (int k = 0; k < 32; ++k) acc += zs[k] * Wd1[k*1024 + n];
  d1[(size_t)m*1024 + n] = f2bf(fmaxf(acc, 0.f));
}

extern "C" void kernel_launch(void* const* d_in, const int* in_sizes, int n_in,
                              void* d_out, int out_size, void* d_ws, size_t ws_size,
                              hipStream_t stream)
{
  (void)in_sizes; (void)n_in; (void)out_size; (void)ws_size;
  const float* x   = (const float*)d_in[0];
  const float* C1  = (const float*)d_in[1];
  const float* W1  = (const float*)d_in[2];
  const float* b1  = (const float*)d_in[3];
  const float* C2  = (const float*)d_in[4];
  const float* W2  = (const float*)d_in[5];
  const float* b2  = (const float*)d_in[6];
  const float* W3  = (const float*)d_in[7];
  const float* b3  = (const float*)d_in[8];
  const float* W4  = (const float*)d_in[9];
  const float* b4  = (const float*)d_in[10];
  const float* Wd1 = (const float*)d_in[11];
  const float* bd1 = (const float*)d_in[12];
  const float* Wd2 = (const float*)d_in[13];
  const float* bd2 = (const float*)d_in[14];
  const float* Wd3 = (const float*)d_in[15];
  const float* bd3 = (const float*)d_in[16];
  float* out = (float*)d_out;

  char* ws = (char*)d_ws;
  size_t off = 0;
  auto alloc = [&](size_t bytes) -> void* {
    void* p = ws + off; off += (bytes + 255) & ~(size_t)255; return p;
  };
  unsigned short* Wt1 = (unsigned short*)alloc((size_t)256*4096*2);   // (W1*C1)^T bf16, N-padded
  unsigned short* Wt2 = (unsigned short*)alloc((size_t)2048*1024*2);  // Wd2^T bf16
  unsigned short* Wt3 = (unsigned short*)alloc((size_t)4096*2048*2);  // Wd3^T bf16
  unsigned short* h1  = (unsigned short*)alloc((size_t)8192*256*2);   // bf16 [8192,256]
  float*          h2  = (float*)         alloc((size_t)8192*10*4);    // fp32 [8192,10]
  unsigned short* h3  = (unsigned short*)alloc((size_t)8192*1024*2);  // bf16
  unsigned short* zb  = (unsigned short*)alloc((size_t)8192*32*2);    // bf16
  unsigned short* d1  = (unsigned short*)alloc((size_t)8192*1024*2);  // bf16
  unsigned short* d2  = (unsigned short*)alloc((size_t)8192*2048*2);  // bf16
  // total ws use ~95 MB

  // weight prep (transpose + bf16 convert, mask fused for W1)
  transpose_bf16<<<dim3(4096/32, 256/32),  256, 0, stream>>>(W1,  C1,      Wt1, 4096, 196,  256);
  transpose_bf16<<<dim3(1024/32, 2048/32), 256, 0, stream>>>(Wd2, nullptr, Wt2, 1024, 2048, 2048);
  transpose_bf16<<<dim3(2048/32, 4096/32), 256, 0, stream>>>(Wd3, nullptr, Wt3, 2048, 4096, 4096);

  // L1: h1 = relu(x @ (W1*C1) + b1)   M=8192 N=256(pad) K=4096, fp32 A staged->bf16
  gemm_mfma<64,64,true,0,true><<<dim3(8192/64, 256/64), 256, 0, stream>>>(
      x, Wt1, b1, 196, h1, 4096, 256);
  // L2: h2 = relu(h1 @ (W2*C2) + b2)  [8192,10]
  layer2_kernel<<<dim3(8192), 64, 0, stream>>>(h1, W2, C2, b2, h2);
  // L3: h3 = relu(h2 @ W3 + b3)       [8192,1024]
  layer3_kernel<<<dim3(8192, 4), 256, 0, stream>>>(h2, W3, b3, h3);
  // L4: z = relu(h3 @ W4 + b4)        [8192,32]
  layer4_kernel<<<dim3(1024), 256, 0, stream>>>(h3, W4, b4, zb);
  // L5: d1 = relu(z @ Wd1 + bd1)      [8192,1024]
  layer5_kernel<<<dim3(8192, 4), 256, 0, stream>>>(zb, Wd1, bd1, d1);
  // L6: d2 = relu(d1 @ Wd2 + bd2)     M=8192 N=2048 K=1024
  gemm_mfma<128,128,false,0,true><<<dim3(8192/128, 2048/128), 256, 0, stream>>>(
      d1, Wt2, bd2, 2048, d2, 1024, 2048);
  // L7: out = sigmoid(d2 @ Wd3 + bd3) M=8192 N=4096 K=2048
  gemm_mfma<128,128,false,1,false><<<dim3(8192/128, 4096/128), 256, 0, stream>>>(
      d2, Wt3, bd3, 4096, out, 2048, 4096);
}

// Round 2
// 687.305 us; speedup vs baseline: 1.0784x; 1.0784x over previous
//
#include <hip/hip_runtime.h>
#include <cstdint>
#include <cstddef>

typedef __attribute__((ext_vector_type(4))) float f32x4;
typedef __attribute__((ext_vector_type(8))) short s16x8;

#define DEVINL __device__ __forceinline__

DEVINL unsigned short f2bf(float f){
  union { float f; unsigned u; } v; v.f = f;
  unsigned r = v.u + 0x7fffu + ((v.u >> 16) & 1u);  // RNE
  return (unsigned short)(r >> 16);
}
DEVINL float bf2f(unsigned short h){
  union { unsigned u; float f; } v; v.u = ((unsigned)h) << 16;
  return v.f;
}
DEVINL void gload_lds16(const void* g, void* l){
  __builtin_amdgcn_global_load_lds((const __attribute__((address_space(1))) void*)g,
                                   (__attribute__((address_space(3))) void*)l, 16, 0, 0);
}

// ---- weight prep: Wt[n][k] = bf16(W[k][n]), zero-pad n>=N ----
__global__ __launch_bounds__(256) void transpose_bf16(
    const float* __restrict__ W, unsigned short* __restrict__ Wt,
    int K, int N, int Npad)
{
  __shared__ unsigned short tile[32][33];
  int k0 = blockIdx.x * 32, n0 = blockIdx.y * 32;
  int tx = threadIdx.x & 31, ty = threadIdx.x >> 5;
  #pragma unroll
  for (int i = 0; i < 4; ++i) {
    int k = k0 + ty + 8*i, n = n0 + tx;
    float v = 0.f;
    if (k < K && n < N) v = W[(size_t)k*N + n];
    tile[ty + 8*i][tx] = f2bf(v);
  }
  __syncthreads();
  #pragma unroll
  for (int i = 0; i < 4; ++i) {
    int n = n0 + ty + 8*i, k = k0 + tx;
    if (n < Npad && k < K) Wt[(size_t)n*K + k] = tile[tx][ty + 8*i];
  }
}

// ---- L1 prep: per-column compaction of the knn mask (exactly 21 nz/col) ----
__global__ __launch_bounds__(64) void build_sparse(
    const float* __restrict__ C1, const float* __restrict__ W1,
    int* __restrict__ idx, float* __restrict__ w)
{
  const int j = blockIdx.x;   // 0..195
  const int l = threadIdx.x;
  if (l < 21) { idx[j*21 + l] = 0; w[j*21 + l] = 0.f; }  // safety vs poison
  __syncthreads();
  int base = 0;
  for (int k0 = 0; k0 < 4096; k0 += 64) {
    float c = C1[(size_t)(k0 + l)*196 + j];
    unsigned long long mask = __ballot(c != 0.f);
    if (c != 0.f) {
      int pos = base + (int)__popcll(mask & ((1ull << l) - 1ull));
      if (pos < 21) {
        idx[j*21 + pos] = k0 + l;
        w[j*21 + pos]   = W1[(size_t)(k0 + l)*196 + j] * c;
      }
    }
    base += (int)__popcll(mask);
  }
}

// ---- L1: h1 = relu(x @ sparse(W1*C1) + b1), 2 rows/block, x read exactly once ----
__global__ __launch_bounds__(256) void layer1_sparse(
    const float* __restrict__ x, const int* __restrict__ idx,
    const float* __restrict__ w, const float* __restrict__ b1,
    unsigned short* __restrict__ h1)
{
  __shared__ float xs[2*4096];
  const int t = threadIdx.x;
  const long m0 = (long)blockIdx.x * 2;
  const float4* src = (const float4*)(x + m0*4096);
  #pragma unroll
  for (int i = 0; i < 8; ++i) ((float4*)xs)[t + i*256] = src[t + i*256];
  __syncthreads();
  for (int e = t; e < 2*196; e += 256) {
    int row = (e >= 196) ? 1 : 0;
    int col = e - row*196;
    const float* xr = xs + row*4096;
    float acc = b1[col];
    #pragma unroll
    for (int i = 0; i < 21; ++i)
      acc += xr[idx[col*21 + i]] * w[col*21 + i];
    h1[(m0 + row)*256 + col] = f2bf(fmaxf(acc, 0.f));
  }
}

// ---- MFMA GEMM: C = act(A[M,K]bf16 * Bt[N,K]^T + bias), XOR-swizzled LDS ----
// ACT: 0 = relu, 1 = sigmoid. Grid: (M/BM, N/BN), 256 threads (4 waves, 2x2).
template<int BM, int BN, int ACT, bool OUT_BF16>
__global__ __launch_bounds__(256) void gemm_mfma(
    const unsigned short* __restrict__ A, const unsigned short* __restrict__ Bt,
    const float* __restrict__ bias,
    void* __restrict__ Cptr, int K, int ldC)
{
  constexpr int BK = 32;                 // bf16 elems; row = 64 B = 4x16B chunks
  constexpr int HM = BM/2, HN = BN/2;
  constexpr int FM = HM/16, FN = HN/16;
  __shared__ __align__(16) unsigned short As[BM*BK];
  __shared__ __align__(16) unsigned short Bs[BN*BK];
  const int tid  = threadIdx.x;
  const int lane = tid & 63;
  const int w    = tid >> 6;
  const int wm = w & 1, wn = w >> 1;
  const int q = lane >> 4, l16 = lane & 15;
  const long m0 = (long)blockIdx.x * BM;
  const long n0 = (long)blockIdx.y * BN;

  f32x4 acc[FM][FN] = {};

  for (int k0 = 0; k0 < K; k0 += BK) {
    // staging: swizzle applied to the per-lane GLOBAL source chunk; LDS dest stays
    // linear (global_load_lds requires wave-uniform base + lane*16)
    #pragma unroll
    for (int it = 0; it < BM/64; ++it) {
      int seg = tid + it*256;
      int row = seg >> 2;
      int c   = (seg & 3) ^ ((row >> 1) & 3);
      gload_lds16(A + (m0 + row)*(long)K + k0 + c*8, (char*)As + seg*16);
    }
    #pragma unroll
    for (int it = 0; it < BN/64; ++it) {
      int seg = tid + it*256;
      int row = seg >> 2;
      int c   = (seg & 3) ^ ((row >> 1) & 3);
      gload_lds16(Bt + (n0 + row)*(long)K + k0 + c*8, (char*)Bs + seg*16);
    }
    __syncthreads();

    s16x8 a[FM], b[FN];
    #pragma unroll
    for (int i = 0; i < FM; ++i) {
      int r = wm*HM + i*16 + l16;
      a[i] = *(const s16x8*)&As[r*BK + (q ^ ((r >> 1) & 3))*8];
    }
    #pragma unroll
    for (int j = 0; j < FN; ++j) {
      int r = wn*HN + j*16 + l16;
      b[j] = *(const s16x8*)&Bs[r*BK + (q ^ ((r >> 1) & 3))*8];
    }
    #pragma unroll
    for (int i = 0; i < FM; ++i)
      #pragma unroll
      for (int j = 0; j < FN; ++j)
        acc[i][j] = __builtin_amdgcn_mfma_f32_16x16x32_bf16(a[i], b[j], acc[i][j], 0, 0, 0);
    __syncthreads();
  }

  // epilogue: D col = lane&15, row = (lane>>4)*4 + r   [m89/m91-verified layout]
  #pragma unroll
  for (int j = 0; j < FN; ++j) {
    long col = n0 + wn*HN + j*16 + l16;
    float bv = bias[col];
    #pragma unroll
    for (int i = 0; i < FM; ++i) {
      #pragma unroll
      for (int r = 0; r < 4; ++r) {
        long row = m0 + wm*HM + i*16 + q*4 + r;
        float v = acc[i][j][r] + bv;
        if (ACT == 0) v = fmaxf(v, 0.f);
        else          v = 1.f / (1.f + __expf(-v));
        if (OUT_BF16) ((unsigned short*)Cptr)[row*(long)ldC + col] = f2bf(v);
        else          ((float*)Cptr)[row*(long)ldC + col] = v;
      }
    }
  }
}

// ---- L2: h2 = relu(h1[M,196] @ (W2*C2)[196,10] + b2), one wave per row, 4 rows/blk ----
__global__ __launch_bounds__(256) void layer2_kernel(
    const unsigned short* __restrict__ h1, const float* __restrict__ W2,
    const float* __restrict__ C2, const float* __restrict__ b2,
    float* __restrict__ h2)
{
  const int m = blockIdx.x * 4 + (threadIdx.x >> 6);
  const int t = threadIdx.x & 63;
  float acc[10];
  #pragma unroll
  for (int n = 0; n < 10; ++n) acc[n] = 0.f;
  for (int k = t; k < 196; k += 64) {
    float a = bf2f(h1[(size_t)m*256 + k]);
    #pragma unroll
    for (int n = 0; n < 10; ++n) acc[n] += a * W2[k*10 + n] * C2[k*10 + n];
  }
  #pragma unroll
  for (int off = 32; off > 0; off >>= 1) {
    #pragma unroll
    for (int n = 0; n < 10; ++n) acc[n] += __shfl_down(acc[n], off, 64);
  }
  if (t == 0) {
    #pragma unroll
    for (int n = 0; n < 10; ++n) h2[(size_t)m*10 + n] = fmaxf(acc[n] + b2[n], 0.f);
  }
}

// ---- L3: h3 = relu(h2[M,10] @ W3[10,1024] + b3) -> bf16 ----
__global__ __launch_bounds__(256) void layer3_kernel(
    const float* __restrict__ h2, const float* __restrict__ W3,
    const float* __restrict__ b3, unsigned short* __restrict__ h3)
{
  const int m = blockIdx.x;
  const int n = blockIdx.y * 256 + threadIdx.x;
  __shared__ float hs[10];
  if (threadIdx.x < 10) hs[threadIdx.x] = h2[(size_t)m*10 + threadIdx.x];
  __syncthreads();
  float acc = b3[n];
  #pragma unroll
  for (int k = 0; k < 10; ++k) acc += hs[k] * W3[k*1024 + n];
  h3[(size_t)m*1024 + n] = f2bf(fmaxf(acc, 0.f));
}

// ---- L4: z = relu(h3[M,1024] @ W4[1024,32] + b4) -> bf16; 8 rows/block ----
__global__ __launch_bounds__(256) void layer4_kernel(
    const unsigned short* __restrict__ h3, const float* __restrict__ W4,
    const float* __restrict__ b4, unsigned short* __restrict__ z)
{
  __shared__ __align__(16) unsigned short hs[8*1024];
  const int t = threadIdx.x;
  const long mb = (long)blockIdx.x * 8;
  const uint4* src = (const uint4*)(h3 + mb*1024);
  #pragma unroll
  for (int i = 0; i < 4; ++i) ((uint4*)hs)[t + i*256] = src[t + i*256];
  __syncthreads();
  const int n = t & 31, ml = t >> 5;
  const unsigned short* hr = hs + ml*1024;
  float acc = b4[n];
  for (int k8 = 0; k8 < 1024; k8 += 8) {
    uint4 hv = *(const uint4*)(hr + k8);
    const unsigned short* hu = (const unsigned short*)&hv;
    #pragma unroll
    for (int j = 0; j < 8; ++j) acc += bf2f(hu[j]) * W4[(k8 + j)*32 + n];
  }
  z[(mb + ml)*32 + n] = f2bf(fmaxf(acc, 0.f));
}

// ---- L5: d1 = relu(z[M,32] @ Wd1[32,1024] + bd1) -> bf16 ----
__global__ __launch_bounds__(256) void layer5_kernel(
    const unsigned short* __restrict__ z, const float* __restrict__ Wd1,
    const float* __restrict__ bd1, unsigned short* __restrict__ d1)
{
  const int m = blockIdx.x;
  const int n = blockIdx.y * 256 + threadIdx.x;
  __shared__ float zs[32];
  if (threadIdx.x < 32) zs[threadIdx.x] = bf2f(z[(size_t)m*32 + threadIdx.x]);
  __syncthreads();
  float acc = bd1[n];
  #pragma unroll
  for (int k = 0; k < 32; ++k) acc += zs[k] * Wd1[k*1024 + n];
  d1[(size_t)m*1024 + n] = f2bf(fmaxf(acc, 0.f));
}

extern "C" void kernel_launch(void* const* d_in, const int* in_sizes, int n_in,
                              void* d_out, int out_size, void* d_ws, size_t ws_size,
                              hipStream_t stream)
{
  (void)in_sizes; (void)n_in; (void)out_size; (void)ws_size;
  const float* x   = (const float*)d_in[0];
  const float* C1  = (const float*)d_in[1];
  const float* W1  = (const float*)d_in[2];
  const float* b1  = (const float*)d_in[3];
  const float* C2  = (const float*)d_in[4];
  const float* W2  = (const float*)d_in[5];
  const float* b2  = (const float*)d_in[6];
  const float* W3  = (const float*)d_in[7];
  const float* b3  = (const float*)d_in[8];
  const float* W4  = (const float*)d_in[9];
  const float* b4  = (const float*)d_in[10];
  const float* Wd1 = (const float*)d_in[11];
  const float* bd1 = (const float*)d_in[12];
  const float* Wd2 = (const float*)d_in[13];
  const float* bd2 = (const float*)d_in[14];
  const float* Wd3 = (const float*)d_in[15];
  const float* bd3 = (const float*)d_in[16];
  float* out = (float*)d_out;

  char* ws = (char*)d_ws;
  size_t off = 0;
  auto alloc = [&](size_t bytes) -> void* {
    void* p = ws + off; off += (bytes + 255) & ~(size_t)255; return p;
  };
  unsigned short* Wt2 = (unsigned short*)alloc((size_t)2048*1024*2);  // Wd2^T bf16
  unsigned short* Wt3 = (unsigned short*)alloc((size_t)4096*2048*2);  // Wd3^T bf16
  int*            s_idx = (int*)         alloc((size_t)196*21*4);
  float*          s_w   = (float*)       alloc((size_t)196*21*4);
  unsigned short* h1  = (unsigned short*)alloc((size_t)8192*256*2);   // bf16 [8192,256]
  float*          h2  = (float*)         alloc((size_t)8192*10*4);    // fp32 [8192,10]
  unsigned short* h3  = (unsigned short*)alloc((size_t)8192*1024*2);  // bf16
  unsigned short* zb  = (unsigned short*)alloc((size_t)8192*32*2);    // bf16
  unsigned short* d1  = (unsigned short*)alloc((size_t)8192*1024*2);  // bf16
  unsigned short* d2  = (unsigned short*)alloc((size_t)8192*2048*2);  // bf16

  // weight prep
  build_sparse<<<dim3(196), 64, 0, stream>>>(C1, W1, s_idx, s_w);
  transpose_bf16<<<dim3(1024/32, 2048/32), 256, 0, stream>>>(Wd2, Wt2, 1024, 2048, 2048);
  transpose_bf16<<<dim3(2048/32, 4096/32), 256, 0, stream>>>(Wd3, Wt3, 2048, 4096, 4096);

  // L1: h1 = relu(x @ (W1*C1) + b1) — sparse gather, x read once
  layer1_sparse<<<dim3(8192/2), 256, 0, stream>>>(x, s_idx, s_w, b1, h1);
  // L2: h2 = relu(h1 @ (W2*C2) + b2)  [8192,10]
  layer2_kernel<<<dim3(8192/4), 256, 0, stream>>>(h1, W2, C2, b2, h2);
  // L3: h3 = relu(h2 @ W3 + b3)       [8192,1024]
  layer3_kernel<<<dim3(8192, 4), 256, 0, stream>>>(h2, W3, b3, h3);
  // L4: z = relu(h3 @ W4 + b4)        [8192,32]
  layer4_kernel<<<dim3(1024), 256, 0, stream>>>(h3, W4, b4, zb);
  // L5: d1 = relu(z @ Wd1 + bd1)      [8192,1024]
  layer5_kernel<<<dim3(8192, 4), 256, 0, stream>>>(zb, Wd1, bd1, d1);
  // L6: d2 = relu(d1 @ Wd2 + bd2)     M=8192 N=2048 K=1024
  gemm_mfma<128,128,0,true><<<dim3(8192/128, 2048/128), 256, 0, stream>>>(
      d1, Wt2, bd2, d2, 1024, 2048);
  // L7: out = sigmoid(d2 @ Wd3 + bd3) M=8192 N=4096 K=2048
  gemm_mfma<128,128,1,false><<<dim3(8192/128, 4096/128), 256, 0, stream>>>(
      d2, Wt3, bd3, out, 2048, 4096);
}

// Round 3
// 539.474 us; speedup vs baseline: 1.3739x; 1.2740x over previous
//
#include <hip/hip_runtime.h>
#include <hip/hip_fp8.h>
#include <cstdint>
#include <cstddef>

typedef __attribute__((ext_vector_type(4))) float f32x4;
typedef __attribute__((ext_vector_type(8))) short s16x8;
typedef __attribute__((ext_vector_type(8))) int i32x8;

#define DEVINL __device__ __forceinline__

DEVINL unsigned short f2bf(float f){
  union { float f; unsigned u; } v; v.f = f;
  unsigned r = v.u + 0x7fffu + ((v.u >> 16) & 1u);  // RNE
  return (unsigned short)(r >> 16);
}
DEVINL float bf2f(unsigned short h){
  union { unsigned u; float f; } v; v.u = ((unsigned)h) << 16;
  return v.f;
}
DEVINL unsigned char f2fp8(float f){
  __hip_fp8_e4m3 t(f);           // OCP e4m3fn, saturating
  return (unsigned char)t.__x;
}
DEVINL void gload_lds16(const void* g, void* l){
  __builtin_amdgcn_global_load_lds((const __attribute__((address_space(1))) void*)g,
                                   (__attribute__((address_space(3))) void*)l, 16, 0, 0);
}

// scale constants: activations stored x2^6, weights x2^4; descale via e8m0 MFMA scales
#define ACT_SCALE 64.0f
#define W_SCALE   16.0f
#define E8M0_ACT  121   // 2^-6
#define E8M0_W    123   // 2^-4

// ---- weight prep: Wt[n][k] = fp8(W[k][n] * 16) ----
__global__ __launch_bounds__(256) void transpose_fp8(
    const float* __restrict__ W, unsigned char* __restrict__ Wt, int K, int N)
{
  __shared__ unsigned char tile[32][33];
  int k0 = blockIdx.x * 32, n0 = blockIdx.y * 32;
  int tx = threadIdx.x & 31, ty = threadIdx.x >> 5;
  #pragma unroll
  for (int i = 0; i < 4; ++i) {
    int k = k0 + ty + 8*i, n = n0 + tx;
    tile[ty + 8*i][tx] = f2fp8(W[(size_t)k*N + n] * W_SCALE);
  }
  __syncthreads();
  #pragma unroll
  for (int i = 0; i < 4; ++i) {
    int n = n0 + ty + 8*i, k = k0 + tx;
    Wt[(size_t)n*K + k] = tile[tx][ty + 8*i];
  }
}

// ---- L1 prep: per-column compaction of the knn mask (exactly 21 nz/col) ----
__global__ __launch_bounds__(64) void build_sparse(
    const float* __restrict__ C1, const float* __restrict__ W1,
    int* __restrict__ idx, float* __restrict__ w)
{
  const int j = blockIdx.x;   // 0..195
  const int l = threadIdx.x;
  if (l < 21) { idx[j*21 + l] = 0; w[j*21 + l] = 0.f; }  // safety vs poison
  __syncthreads();
  int base = 0;
  for (int k0 = 0; k0 < 4096; k0 += 64) {
    float c = C1[(size_t)(k0 + l)*196 + j];
    unsigned long long mask = __ballot(c != 0.f);
    if (c != 0.f) {
      int pos = base + (int)__popcll(mask & ((1ull << l) - 1ull));
      if (pos < 21) {
        idx[j*21 + pos] = k0 + l;
        w[j*21 + pos]   = W1[(size_t)(k0 + l)*196 + j] * c;
      }
    }
    base += (int)__popcll(mask);
  }
}

// ---- L1: h1 = relu(x @ sparse(W1*C1) + b1), 2 rows/block, x read exactly once ----
__global__ __launch_bounds__(256) void layer1_sparse(
    const float* __restrict__ x, const int* __restrict__ idx,
    const float* __restrict__ w, const float* __restrict__ b1,
    unsigned short* __restrict__ h1)
{
  __shared__ float xs[2*4096];
  const int t = threadIdx.x;
  const long m0 = (long)blockIdx.x * 2;
  const float4* src = (const float4*)(x + m0*4096);
  #pragma unroll
  for (int i = 0; i < 8; ++i) ((float4*)xs)[t + i*256] = src[t + i*256];
  __syncthreads();
  for (int e = t; e < 2*196; e += 256) {
    int row = (e >= 196) ? 1 : 0;
    int col = e - row*196;
    const float* xr = xs + row*4096;
    float acc = b1[col];
    #pragma unroll
    for (int i = 0; i < 21; ++i)
      acc += xr[idx[col*21 + i]] * w[col*21 + i];
    h1[(m0 + row)*256 + col] = f2bf(fmaxf(acc, 0.f));
  }
}

// ---- MX-fp8 MFMA GEMM: C = act(A[M,K] * Bt[N,K]^T + bias) ----
// A, Bt fp8 e4m3 (A holds value*2^6, Bt holds value*2^4; HW descales via e8m0).
// ACT 0: relu -> fp8 x2^6 store (LDS-repacked, coalesced); ACT 1: sigmoid -> fp32.
// Grid: (M/128, N/128), 256 threads (4 waves, 2x2). BK = 128 bytes/row = 8 chunks.
template<int ACT>
__global__ __launch_bounds__(256) void gemm_fp8(
    const unsigned char* __restrict__ A, const unsigned char* __restrict__ Bt,
    const float* __restrict__ bias, void* __restrict__ Cptr, int K, int ldC)
{
  constexpr int BM = 128, BN = 128, BK = 128;
  constexpr int HM = 64, HN = 64, FM = 4, FN = 4;
  __shared__ __align__(16) unsigned char As[BM*BK];
  __shared__ __align__(16) unsigned char Bs[BN*BK];
  const int tid  = threadIdx.x;
  const int lane = tid & 63;
  const int w    = tid >> 6;
  const int wm = w & 1, wn = w >> 1;
  const int q = lane >> 4, l16 = lane & 15;
  const long m0 = (long)blockIdx.x * BM;
  const long n0 = (long)blockIdx.y * BN;

  f32x4 acc[FM][FN] = {};

  for (int k0 = 0; k0 < K; k0 += BK) {
    // stage: XOR-swizzle chunk at the GLOBAL source; LDS dest linear (HW requirement)
    #pragma unroll
    for (int it = 0; it < 4; ++it) {
      int seg = tid + it*256;               // 1024 segs of 16B = 16KB tile
      int row = seg >> 3;
      int cg  = (seg & 7) ^ (row & 7);
      gload_lds16(A + (m0 + row)*(long)K + k0 + cg*16, As + seg*16);
    }
    #pragma unroll
    for (int it = 0; it < 4; ++it) {
      int seg = tid + it*256;
      int row = seg >> 3;
      int cg  = (seg & 7) ^ (row & 7);
      gload_lds16(Bt + (n0 + row)*(long)K + k0 + cg*16, Bs + seg*16);
    }
    __syncthreads();

    // fragments: lane holds k = q*32 .. q*32+31 of row (wm*HM + i*16 + l16)
    i32x8 a[FM], b[FN];
    #pragma unroll
    for (int i = 0; i < FM; ++i) {
      int r = wm*HM + i*16 + l16;
      const uint4* p = (const uint4*)(As + r*BK);
      union { uint4 v[2]; i32x8 f; } u;
      u.v[0] = p[(2*q)   ^ (r & 7)];
      u.v[1] = p[(2*q+1) ^ (r & 7)];
      a[i] = u.f;
    }
    #pragma unroll
    for (int j = 0; j < FN; ++j) {
      int r = wn*HN + j*16 + l16;
      const uint4* p = (const uint4*)(Bs + r*BK);
      union { uint4 v[2]; i32x8 f; } u;
      u.v[0] = p[(2*q)   ^ (r & 7)];
      u.v[1] = p[(2*q+1) ^ (r & 7)];
      b[j] = u.f;
    }
    #pragma unroll
    for (int i = 0; i < FM; ++i)
      #pragma unroll
      for (int j = 0; j < FN; ++j)
        acc[i][j] = __builtin_amdgcn_mfma_scale_f32_16x16x128_f8f6f4(
            a[i], b[j], acc[i][j], 0, 0, 0, E8M0_ACT, 0, E8M0_W);
    __syncthreads();
  }

  // epilogue: D col = lane&15, row = (lane>>4)*4 + r  [m89/m91 layout, shape-determined]
  if constexpr (ACT == 0) {
    // relu -> fp8 x2^6, repack through As for coalesced 16B global stores
    #pragma unroll
    for (int j = 0; j < FN; ++j) {
      int cl = wn*HN + j*16 + l16;
      float bv = bias[n0 + cl];
      #pragma unroll
      for (int i = 0; i < FM; ++i) {
        #pragma unroll
        for (int r = 0; r < 4; ++r) {
          int rl = wm*HM + i*16 + q*4 + r;
          float v = fmaxf(acc[i][j][r] + bv, 0.f) * ACT_SCALE;
          As[rl*BN + cl] = f2fp8(v);
        }
      }
    }
    __syncthreads();
    unsigned char* C = (unsigned char*)Cptr;
    #pragma unroll
    for (int it = 0; it < 4; ++it) {
      int seg = tid + it*256;
      int row = seg >> 3;
      *(uint4*)(C + (m0 + row)*(long)ldC + n0 + (seg & 7)*16) = ((const uint4*)As)[seg];
    }
  } else {
    float* C = (float*)Cptr;
    #pragma unroll
    for (int j = 0; j < FN; ++j) {
      long col = n0 + wn*HN + j*16 + l16;
      float bv = bias[col];
      #pragma unroll
      for (int i = 0; i < FM; ++i) {
        #pragma unroll
        for (int r = 0; r < 4; ++r) {
          long row = m0 + wm*HM + i*16 + q*4 + r;
          float v = acc[i][j][r] + bv;
          C[row*(long)ldC + col] = 1.f / (1.f + __expf(-v));
        }
      }
    }
  }
}

// ---- L2: h2 = relu(h1[M,196] @ (W2*C2)[196,10] + b2), one wave/row, 4 rows/blk ----
__global__ __launch_bounds__(256) void layer2_kernel(
    const unsigned short* __restrict__ h1, const float* __restrict__ W2,
    const float* __restrict__ C2, const float* __restrict__ b2,
    float* __restrict__ h2)
{
  const int m = blockIdx.x * 4 + (threadIdx.x >> 6);
  const int t = threadIdx.x & 63;
  float acc[10];
  #pragma unroll
  for (int n = 0; n < 10; ++n) acc[n] = 0.f;
  for (int k = t; k < 196; k += 64) {
    float a = bf2f(h1[(size_t)m*256 + k]);
    #pragma unroll
    for (int n = 0; n < 10; ++n) acc[n] += a * W2[k*10 + n] * C2[k*10 + n];
  }
  #pragma unroll
  for (int off = 32; off > 0; off >>= 1) {
    #pragma unroll
    for (int n = 0; n < 10; ++n) acc[n] += __shfl_down(acc[n], off, 64);
  }
  if (t == 0) {
    #pragma unroll
    for (int n = 0; n < 10; ++n) h2[(size_t)m*10 + n] = fmaxf(acc[n] + b2[n], 0.f);
  }
}

// ---- L3: h3 = relu(h2[M,10] @ W3[10,1024] + b3) -> bf16 ----
__global__ __launch_bounds__(256) void layer3_kernel(
    const float* __restrict__ h2, const float* __restrict__ W3,
    const float* __restrict__ b3, unsigned short* __restrict__ h3)
{
  const int m = blockIdx.x;
  const int n = blockIdx.y * 256 + threadIdx.x;
  __shared__ float hs[10];
  if (threadIdx.x < 10) hs[threadIdx.x] = h2[(size_t)m*10 + threadIdx.x];
  __syncthreads();
  float acc = b3[n];
  #pragma unroll
  for (int k = 0; k < 10; ++k) acc += hs[k] * W3[k*1024 + n];
  h3[(size_t)m*1024 + n] = f2bf(fmaxf(acc, 0.f));
}

// ---- L4: z = relu(h3[M,1024] @ W4[1024,32] + b4) -> bf16; 8 rows/block ----
__global__ __launch_bounds__(256) void layer4_kernel(
    const unsigned short* __restrict__ h3, const float* __restrict__ W4,
    const float* __restrict__ b4, unsigned short* __restrict__ z)
{
  __shared__ __align__(16) unsigned short hs[8*1024];
  const int t = threadIdx.x;
  const long mb = (long)blockIdx.x * 8;
  const uint4* src = (const uint4*)(h3 + mb*1024);
  #pragma unroll
  for (int i = 0; i < 4; ++i) ((uint4*)hs)[t + i*256] = src[t + i*256];
  __syncthreads();
  const int n = t & 31, ml = t >> 5;
  const unsigned short* hr = hs + ml*1024;
  float acc = b4[n];
  for (int k8 = 0; k8 < 1024; k8 += 8) {
    uint4 hv = *(const uint4*)(hr + k8);
    const unsigned short* hu = (const unsigned short*)&hv;
    #pragma unroll
    for (int j = 0; j < 8; ++j) acc += bf2f(hu[j]) * W4[(k8 + j)*32 + n];
  }
  z[(mb + ml)*32 + n] = f2bf(fmaxf(acc, 0.f));
}

// ---- L5: d1 = relu(z[M,32] @ Wd1[32,1024] + bd1) -> fp8 x2^6 ----
__global__ __launch_bounds__(256) void layer5_kernel(
    const unsigned short* __restrict__ z, const float* __restrict__ Wd1,
    const float* __restrict__ bd1, unsigned char* __restrict__ d1)
{
  const int m = blockIdx.x;
  const int n = blockIdx.y * 256 + threadIdx.x;
  __shared__ float zs[32];
  if (threadIdx.x < 32) zs[threadIdx.x] = bf2f(z[(size_t)m*32 + threadIdx.x]);
  __syncthreads();
  float acc = bd1[n];
  #pragma unroll
  for (int k = 0; k < 32; ++k) acc += zs[k] * Wd1[k*1024 + n];
  d1[(size_t)m*1024 + n] = f2fp8(fmaxf(acc, 0.f) * ACT_SCALE);
}

extern "C" void kernel_launch(void* const* d_in, const int* in_sizes, int n_in,
                              void* d_out, int out_size, void* d_ws, size_t ws_size,
                              hipStream_t stream)
{
  (void)in_sizes; (void)n_in; (void)out_size; (void)ws_size;
  const float* x   = (const float*)d_in[0];
  const float* C1  = (const float*)d_in[1];
  const float* W1  = (const float*)d_in[2];
  const float* b1  = (const float*)d_in[3];
  const float* C2  = (const float*)d_in[4];
  const float* W2  = (const float*)d_in[5];
  const float* b2  = (const float*)d_in[6];
  const float* W3  = (const float*)d_in[7];
  const float* b3  = (const float*)d_in[8];
  const float* W4  = (const float*)d_in[9];
  const float* b4  = (const float*)d_in[10];
  const float* Wd1 = (const float*)d_in[11];
  const float* bd1 = (const float*)d_in[12];
  const float* Wd2 = (const float*)d_in[13];
  const float* bd2 = (const float*)d_in[14];
  const float* Wd3 = (const float*)d_in[15];
  const float* bd3 = (const float*)d_in[16];
  float* out = (float*)d_out;

  char* ws = (char*)d_ws;
  size_t off = 0;
  auto alloc = [&](size_t bytes) -> void* {
    void* p = ws + off; off += (bytes + 255) & ~(size_t)255; return p;
  };
  unsigned char* Wt2 = (unsigned char*)alloc((size_t)2048*1024);   // Wd2^T fp8 x16
  unsigned char* Wt3 = (unsigned char*)alloc((size_t)4096*2048);   // Wd3^T fp8 x16
  int*           s_idx = (int*)        alloc((size_t)196*21*4);
  float*         s_w   = (float*)      alloc((size_t)196*21*4);
  unsigned short* h1 = (unsigned short*)alloc((size_t)8192*256*2); // bf16
  float*          h2 = (float*)         alloc((size_t)8192*10*4);  // fp32
  unsigned short* h3 = (unsigned short*)alloc((size_t)8192*1024*2);// bf16
  unsigned short* zb = (unsigned short*)alloc((size_t)8192*32*2);  // bf16
  unsigned char*  d1 = (unsigned char*) alloc((size_t)8192*1024);  // fp8 x2^6
  unsigned char*  d2 = (unsigned char*) alloc((size_t)8192*2048);  // fp8 x2^6

  // prep
  build_sparse<<<dim3(196), 64, 0, stream>>>(C1, W1, s_idx, s_w);
  transpose_fp8<<<dim3(1024/32, 2048/32), 256, 0, stream>>>(Wd2, Wt2, 1024, 2048);
  transpose_fp8<<<dim3(2048/32, 4096/32), 256, 0, stream>>>(Wd3, Wt3, 2048, 4096);

  // L1: h1 = relu(x @ (W1*C1) + b1) — sparse gather, x read once
  layer1_sparse<<<dim3(8192/2), 256, 0, stream>>>(x, s_idx, s_w, b1, h1);
  // L2..L5
  layer2_kernel<<<dim3(8192/4), 256, 0, stream>>>(h1, W2, C2, b2, h2);
  layer3_kernel<<<dim3(8192, 4), 256, 0, stream>>>(h2, W3, b3, h3);
  layer4_kernel<<<dim3(1024), 256, 0, stream>>>(h3, W4, b4, zb);
  layer5_kernel<<<dim3(8192, 4), 256, 0, stream>>>(zb, Wd1, bd1, d1);
  // L6: d2 = relu(d1 @ Wd2 + bd2)  M=8192 N=2048 K=1024  (MX-fp8)
  gemm_fp8<0><<<dim3(8192/128, 2048/128), 256, 0, stream>>>(
      d1, Wt2, bd2, d2, 1024, 2048);
  // L7: out = sigmoid(d2 @ Wd3 + bd3)  M=8192 N=4096 K=2048  (MX-fp8)
  gemm_fp8<1><<<dim3(8192/128, 4096/128), 256, 0, stream>>>(
      d2, Wt3, bd3, out, 2048, 4096);
}

// Round 4
// 464.943 us; speedup vs baseline: 1.5941x; 1.1603x over previous
//
#include <hip/hip_runtime.h>
#include <hip/hip_fp8.h>
#include <cstdint>
#include <cstddef>

typedef __attribute__((ext_vector_type(4))) float f32x4;
typedef __attribute__((ext_vector_type(8))) int i32x8;

#define DEVINL __device__ __forceinline__

DEVINL unsigned short f2bf(float f){
  union { float f; unsigned u; } v; v.f = f;
  unsigned r = v.u + 0x7fffu + ((v.u >> 16) & 1u);  // RNE
  return (unsigned short)(r >> 16);
}
DEVINL float bf2f(unsigned short h){
  union { unsigned u; float f; } v; v.u = ((unsigned)h) << 16;
  return v.f;
}
DEVINL unsigned char f2fp8(float f){
  __hip_fp8_e4m3 t(f);           // OCP e4m3fn, saturating
  return (unsigned char)t.__x;
}
DEVINL void gload_lds16(const void* g, void* l){
  __builtin_amdgcn_global_load_lds((const __attribute__((address_space(1))) void*)g,
                                   (__attribute__((address_space(3))) void*)l, 16, 0, 0);
}

// scale constants: activations stored x2^6, weights x2^4; descale via e8m0 MFMA scales
#define ACT_SCALE 64.0f
#define W_SCALE   16.0f
#define E8M0_ACT  121   // 2^-6
#define E8M0_W    123   // 2^-4

// ---- weight prep: Wt[n][k] = fp8(W[k][n] * 16) ----
__global__ __launch_bounds__(256) void transpose_fp8(
    const float* __restrict__ W, unsigned char* __restrict__ Wt, int K, int N)
{
  __shared__ unsigned char tile[32][33];
  int k0 = blockIdx.x * 32, n0 = blockIdx.y * 32;
  int tx = threadIdx.x & 31, ty = threadIdx.x >> 5;
  #pragma unroll
  for (int i = 0; i < 4; ++i) {
    int k = k0 + ty + 8*i, n = n0 + tx;
    tile[ty + 8*i][tx] = f2fp8(W[(size_t)k*N + n] * W_SCALE);
  }
  __syncthreads();
  #pragma unroll
  for (int i = 0; i < 4; ++i) {
    int n = n0 + ty + 8*i, k = k0 + tx;
    Wt[(size_t)n*K + k] = tile[tx][ty + 8*i];
  }
}

// ---- L1 prep: compact knn mask column j -> 21 packed (idx<<16 | bf16(W1)) ----
// 4 waves, two-pass (count then place); slot order within column is irrelevant
// because the consumer only sums the terms.
__global__ __launch_bounds__(256) void build_sparse(
    const float* __restrict__ C1, const float* __restrict__ W1,
    unsigned* __restrict__ packed)
{
  const int j = blockIdx.x;            // 0..195
  const int w = threadIdx.x >> 6, l = threadIdx.x & 63;
  __shared__ int wcnt[4], wbase[4];
  // pass 1: per-wave nonzero count
  int cnt = 0;
  #pragma unroll 4
  for (int it = 0; it < 16; ++it) {
    int k = w*1024 + it*64 + l;
    float c = C1[(size_t)k*196 + j];
    unsigned long long m = __ballot(c != 0.f);
    cnt += (int)__popcll(m);
  }
  if (l == 0) wcnt[w] = cnt;
  __syncthreads();
  if (threadIdx.x < 21) packed[j*21 + threadIdx.x] = 0;  // safety vs poison
  if (threadIdx.x == 0) {
    int b = 0;
    #pragma unroll
    for (int i = 0; i < 4; ++i) { wbase[i] = b; b += wcnt[i]; }
  }
  __syncthreads();
  // pass 2: place (L2-hot reload)
  int base = wbase[w];
  #pragma unroll 4
  for (int it = 0; it < 16; ++it) {
    int k = w*1024 + it*64 + l;
    float c = C1[(size_t)k*196 + j];
    unsigned long long m = __ballot(c != 0.f);
    if (c != 0.f) {
      int pos = base + (int)__popcll(m & ((1ull << l) - 1ull));
      if (pos < 21)
        packed[j*21 + pos] = ((unsigned)k << 16)
                           | (unsigned)f2bf(W1[(size_t)k*196 + j] * c);
    }
    base += (int)__popcll(m);
  }
}

// ---- L1: h1 = relu(x @ sparse(W1*C1) + b1), 2 rows/block, x read exactly once ----
__global__ __launch_bounds__(256) void layer1_sparse(
    const float* __restrict__ x, const unsigned* __restrict__ packed,
    const float* __restrict__ b1, unsigned short* __restrict__ h1)
{
  __shared__ float xs[2*4096];
  const int t = threadIdx.x;
  const long m0 = (long)blockIdx.x * 2;
  const float4* src = (const float4*)(x + m0*4096);
  #pragma unroll
  for (int i = 0; i < 8; ++i) ((float4*)xs)[t + i*256] = src[t + i*256];
  __syncthreads();
  for (int e = t; e < 2*196; e += 256) {
    int row = (e >= 196) ? 1 : 0;
    int col = e - row*196;
    const float* xr = xs + row*4096;
    float acc = b1[col];
    #pragma unroll
    for (int i = 0; i < 21; ++i) {
      unsigned p = packed[col*21 + i];          // L1-hot 16.5 KB table
      acc += xr[p >> 16] * bf2f((unsigned short)(p & 0xffffu));
    }
    h1[(m0 + row)*256 + col] = f2bf(fmaxf(acc, 0.f));
  }
}

// ---- MX-fp8 MFMA GEMM: C = act(A[M,K] * Bt[N,K]^T + bias) ----
// LDS position of global 16B chunk g in row r: p = (5g + r) & 7  (multiplicative
// swizzle: the fragment pair {2q,2q+1} maps 5 apart -> no 32B merge, full bank
// spread). Staging inverts at the GLOBAL source: g = (5d + 3r) & 7.
// ACT 0: relu -> fp8 x2^6 (LDS-repacked, stride 144, coalesced 16B stores);
// ACT 1: sigmoid -> fp32. Grid (M/128, N/128), 256 threads (2x2 waves).
template<int ACT>
__global__ __launch_bounds__(256) void gemm_fp8(
    const unsigned char* __restrict__ A, const unsigned char* __restrict__ Bt,
    const float* __restrict__ bias, void* __restrict__ Cptr, int K, int ldC)
{
  constexpr int BM = 128, BN = 128, BK = 128;
  constexpr int HM = 64, HN = 64, FM = 4, FN = 4;
  __shared__ __align__(16) unsigned char smem[32768];
  unsigned char* As = smem;
  unsigned char* Bs = smem + 16384;
  const int tid  = threadIdx.x;
  const int lane = tid & 63;
  const int w    = tid >> 6;
  const int wm = w & 1, wn = w >> 1;
  const int q = lane >> 4, l16 = lane & 15;
  const long m0 = (long)blockIdx.x * BM;
  const long n0 = (long)blockIdx.y * BN;

  f32x4 acc[FM][FN] = {};

  for (int k0 = 0; k0 < K; k0 += BK) {
    #pragma unroll
    for (int it = 0; it < 4; ++it) {
      int seg = tid + it*256;
      int row = seg >> 3;
      int g   = (5*(seg & 7) + 3*row) & 7;
      gload_lds16(A + (m0 + row)*(long)K + k0 + g*16, As + seg*16);
    }
    #pragma unroll
    for (int it = 0; it < 4; ++it) {
      int seg = tid + it*256;
      int row = seg >> 3;
      int g   = (5*(seg & 7) + 3*row) & 7;
      gload_lds16(Bt + (n0 + row)*(long)K + k0 + g*16, Bs + seg*16);
    }
    __syncthreads();

    // fragment: lane holds k = q*32..q*32+31 of row (verified by R3 absmax=0)
    i32x8 a[FM], b[FN];
    #pragma unroll
    for (int i = 0; i < FM; ++i) {
      int r = wm*HM + i*16 + l16;
      const uint4* p = (const uint4*)(As + r*BK);
      int c0 = (2*q + r) & 7;
      union { uint4 v[2]; i32x8 f; } u;
      u.v[0] = p[c0];
      u.v[1] = p[(c0 + 5) & 7];
      a[i] = u.f;
    }
    #pragma unroll
    for (int j = 0; j < FN; ++j) {
      int r = wn*HN + j*16 + l16;
      const uint4* p = (const uint4*)(Bs + r*BK);
      int c0 = (2*q + r) & 7;
      union { uint4 v[2]; i32x8 f; } u;
      u.v[0] = p[c0];
      u.v[1] = p[(c0 + 5) & 7];
      b[j] = u.f;
    }
    #pragma unroll
    for (int i = 0; i < FM; ++i)
      #pragma unroll
      for (int j = 0; j < FN; ++j)
        acc[i][j] = __builtin_amdgcn_mfma_scale_f32_16x16x128_f8f6f4(
            a[i], b[j], acc[i][j], 0, 0, 0, E8M0_ACT, 0, E8M0_W);
    __syncthreads();
  }

  // epilogue: D col = lane&15, row = (lane>>4)*4 + r  [m89/m91 layout]
  if constexpr (ACT == 0) {
    // relu -> fp8 x2^6, repack via smem (row stride 144 breaks bank aliasing)
    #pragma unroll
    for (int j = 0; j < FN; ++j) {
      int cl = wn*HN + j*16 + l16;
      float bv = bias[n0 + cl];
      #pragma unroll
      for (int i = 0; i < FM; ++i) {
        #pragma unroll
        for (int r = 0; r < 4; ++r) {
          int rl = wm*HM + i*16 + q*4 + r;
          smem[rl*144 + cl] = f2fp8(fmaxf(acc[i][j][r] + bv, 0.f) * ACT_SCALE);
        }
      }
    }
    __syncthreads();
    unsigned char* C = (unsigned char*)Cptr;
    #pragma unroll
    for (int it = 0; it < 4; ++it) {
      int seg = tid + it*256;
      int row = seg >> 3;
      *(uint4*)(C + (m0 + row)*(long)ldC + n0 + (seg & 7)*16) =
          *(const uint4*)(smem + row*144 + (seg & 7)*16);
    }
  } else {
    float* C = (float*)Cptr;
    #pragma unroll
    for (int j = 0; j < FN; ++j) {
      long col = n0 + wn*HN + j*16 + l16;
      float bv = bias[col];
      #pragma unroll
      for (int i = 0; i < FM; ++i) {
        #pragma unroll
        for (int r = 0; r < 4; ++r) {
          long row = m0 + wm*HM + i*16 + q*4 + r;
          float v = acc[i][j][r] + bv;
          C[row*(long)ldC + col] = 1.f / (1.f + __expf(-v));
        }
      }
    }
  }
}

// ---- fused L2+L3+L4+L5: h1[4 rows] -> d1 (fp8 x2^6), all intermediates in LDS ----
// grid 2048 blocks x 256 threads (4 waves). Per-block weight traffic: W2C2 16KB,
// W3 40KB, W4 128KB, Wd1 128KB (each read once per block, L2-resident).
__global__ __launch_bounds__(256) void layer2345(
    const unsigned short* __restrict__ h1,
    const float* __restrict__ W2, const float* __restrict__ C2, const float* __restrict__ b2,
    const float* __restrict__ W3, const float* __restrict__ b3,
    const float* __restrict__ W4, const float* __restrict__ b4,
    const float* __restrict__ Wd1, const float* __restrict__ bd1,
    unsigned char* __restrict__ d1)
{
  __shared__ float h1s[4][200];
  __shared__ float h2s[4][10];
  __shared__ float h3s[4][1024];
  __shared__ float part[8][128];
  __shared__ float zs[4][32];
  const int t = threadIdx.x;
  const int w = t >> 6, l = t & 63;
  const long m0 = (long)blockIdx.x * 4;

  // load h1 rows (bf16 -> f32)
  for (int e = t; e < 4*196; e += 256) {
    int row = e / 196, col = e - row*196;
    h1s[row][col] = bf2f(h1[(m0 + row)*256 + col]);
  }
  __syncthreads();

  // L2: h2[r][10], wave w handles row w
  {
    float acc[10];
    #pragma unroll
    for (int n = 0; n < 10; ++n) acc[n] = 0.f;
    #pragma unroll
    for (int it = 0; it < 4; ++it) {
      int k = l + it*64;
      if (k < 196) {
        float a = h1s[w][k];
        #pragma unroll
        for (int n = 0; n < 10; ++n) acc[n] += a * W2[k*10 + n] * C2[k*10 + n];
      }
    }
    #pragma unroll
    for (int off = 32; off > 0; off >>= 1) {
      #pragma unroll
      for (int n = 0; n < 10; ++n) acc[n] += __shfl_down(acc[n], off, 64);
    }
    if (l < 10) h2s[w][l] = fmaxf(acc[l] + b2[l], 0.f);
  }
  __syncthreads();

  // L3: h3[r][1024]; wave w covers n = w*256 .. w*256+255, all 4 rows per thread
  #pragma unroll
  for (int jj = 0; jj < 4; ++jj) {
    int n = w*256 + jj*64 + l;
    float a0 = b3[n], a1 = a0, a2 = a0, a3 = a0;
    #pragma unroll
    for (int k = 0; k < 10; ++k) {
      float wv = W3[k*1024 + n];
      a0 += h2s[0][k]*wv; a1 += h2s[1][k]*wv;
      a2 += h2s[2][k]*wv; a3 += h2s[3][k]*wv;
    }
    h3s[0][n] = fmaxf(a0, 0.f); h3s[1][n] = fmaxf(a1, 0.f);
    h3s[2][n] = fmaxf(a2, 0.f); h3s[3][n] = fmaxf(a3, 0.f);
  }
  __syncthreads();

  // L4: z[r][32]; thread (kg = t>>5 in 0..7, n = t&31) covers k = kg*128..+127
  {
    int n = t & 31, kg = t >> 5;
    float a0 = 0.f, a1 = 0.f, a2 = 0.f, a3 = 0.f;
    for (int k = kg*128; k < kg*128 + 128; ++k) {
      float wv = W4[k*32 + n];
      a0 += h3s[0][k]*wv; a1 += h3s[1][k]*wv;
      a2 += h3s[2][k]*wv; a3 += h3s[3][k]*wv;
    }
    part[kg][0*32 + n] = a0; part[kg][1*32 + n] = a1;
    part[kg][2*32 + n] = a2; part[kg][3*32 + n] = a3;
  }
  __syncthreads();
  if (t < 128) {
    float s = 0.f;
    #pragma unroll
    for (int kg = 0; kg < 8; ++kg) s += part[kg][t];
    zs[t >> 5][t & 31] = fmaxf(s + b4[t & 31], 0.f);
  }
  __syncthreads();

  // L5: d1[r][1024] fp8 x2^6; wave w covers n = w*256..+255, 4 rows per thread
  #pragma unroll
  for (int jj = 0; jj < 4; ++jj) {
    int n = w*256 + jj*64 + l;
    float a0 = bd1[n], a1 = a0, a2 = a0, a3 = a0;
    #pragma unroll
    for (int k = 0; k < 32; ++k) {
      float wv = Wd1[k*1024 + n];
      a0 += zs[0][k]*wv; a1 += zs[1][k]*wv;
      a2 += zs[2][k]*wv; a3 += zs[3][k]*wv;
    }
    d1[(m0 + 0)*1024 + n] = f2fp8(fmaxf(a0, 0.f) * ACT_SCALE);
    d1[(m0 + 1)*1024 + n] = f2fp8(fmaxf(a1, 0.f) * ACT_SCALE);
    d1[(m0 + 2)*1024 + n] = f2fp8(fmaxf(a2, 0.f) * ACT_SCALE);
    d1[(m0 + 3)*1024 + n] = f2fp8(fmaxf(a3, 0.f) * ACT_SCALE);
  }
}

extern "C" void kernel_launch(void* const* d_in, const int* in_sizes, int n_in,
                              void* d_out, int out_size, void* d_ws, size_t ws_size,
                              hipStream_t stream)
{
  (void)in_sizes; (void)n_in; (void)out_size; (void)ws_size;
  const float* x   = (const float*)d_in[0];
  const float* C1  = (const float*)d_in[1];
  const float* W1  = (const float*)d_in[2];
  const float* b1  = (const float*)d_in[3];
  const float* C2  = (const float*)d_in[4];
  const float* W2  = (const float*)d_in[5];
  const float* b2  = (const float*)d_in[6];
  const float* W3  = (const float*)d_in[7];
  const float* b3  = (const float*)d_in[8];
  const float* W4  = (const float*)d_in[9];
  const float* b4  = (const float*)d_in[10];
  const float* Wd1 = (const float*)d_in[11];
  const float* bd1 = (const float*)d_in[12];
  const float* Wd2 = (const float*)d_in[13];
  const float* bd2 = (const float*)d_in[14];
  const float* Wd3 = (const float*)d_in[15];
  const float* bd3 = (const float*)d_in[16];
  float* out = (float*)d_out;

  char* ws = (char*)d_ws;
  size_t off = 0;
  auto alloc = [&](size_t bytes) -> void* {
    void* p = ws + off; off += (bytes + 255) & ~(size_t)255; return p;
  };
  unsigned char* Wt2 = (unsigned char*)alloc((size_t)2048*1024);   // Wd2^T fp8 x16
  unsigned char* Wt3 = (unsigned char*)alloc((size_t)4096*2048);   // Wd3^T fp8 x16
  unsigned*      pk  = (unsigned*)     alloc((size_t)196*21*4);    // packed sparse W1C1
  unsigned short* h1 = (unsigned short*)alloc((size_t)8192*256*2); // bf16
  unsigned char*  d1 = (unsigned char*) alloc((size_t)8192*1024);  // fp8 x2^6
  unsigned char*  d2 = (unsigned char*) alloc((size_t)8192*2048);  // fp8 x2^6

  // prep
  build_sparse<<<dim3(196), 256, 0, stream>>>(C1, W1, pk);
  transpose_fp8<<<dim3(1024/32, 2048/32), 256, 0, stream>>>(Wd2, Wt2, 1024, 2048);
  transpose_fp8<<<dim3(2048/32, 4096/32), 256, 0, stream>>>(Wd3, Wt3, 2048, 4096);

  // L1: h1 = relu(x @ (W1*C1) + b1) — sparse gather, x read once
  layer1_sparse<<<dim3(8192/2), 256, 0, stream>>>(x, pk, b1, h1);
  // L2..L5 fused
  layer2345<<<dim3(8192/4), 256, 0, stream>>>(h1, W2, C2, b2, W3, b3, W4, b4,
                                              Wd1, bd1, d1);
  // L6: d2 = relu(d1 @ Wd2 + bd2)  M=8192 N=2048 K=1024  (MX-fp8)
  gemm_fp8<0><<<dim3(8192/128, 2048/128), 256, 0, stream>>>(
      d1, Wt2, bd2, d2, 1024, 2048);
  // L7: out = sigmoid(d2 @ Wd3 + bd3)  M=8192 N=4096 K=2048  (MX-fp8)
  gemm_fp8<1><<<dim3(8192/128, 4096/128), 256, 0, stream>>>(
      d2, Wt3, bd3, out, 2048, 4096);
}